// Round 7
// baseline (319.683 us; speedup 1.0000x reference)
//
#include <hip/hip_runtime.h>
#include <hip/hip_bf16.h>

#define N_NODES 100000
#define N_EDGES 1600000
#define IN_CH 256
#define OUT_CH 128

#define BSZ 64             // nodes per bucket (power of 2)
#define NBUCK 1563         // ceil(N_NODES / BSZ)
#define BCAP 1408          // bucket capacity: mean 1024, sd ~32 -> 12 sigma headroom
#define CSC 4096           // edges per block, scatter
#define SCB 391            // scatter blocks = ceil(N_EDGES / CSC)
#define PREPB 64           // init blocks (64 x 512 = 32768 W elements)

#define GEMM_ROWS 32       // rows per gemm block
#define GEMB 3125          // N_NODES / GEMM_ROWS

typedef __attribute__((ext_vector_type(8))) short short8;
typedef __attribute__((ext_vector_type(4))) float floatx4;
typedef __attribute__((ext_vector_type(2))) float float2v;

union bfu { __hip_bfloat16 b; unsigned short u; };

__device__ inline unsigned short f2bf(float v) {
    bfu cv; cv.b = __float2bfloat16(v); return cv.u;
}
__device__ inline float bf2f(unsigned short u) {
    bfu cv; cv.u = u; return __bfloat162float(cv.b);
}

// acc += dnp * unpacked(g): one v_pk_fma_f32 for both channels
__device__ inline void pkfma(float2v& acc, unsigned g, float2v dnp) {
    float2v v;
    v.x = __uint_as_float(g << 16);
    v.y = __uint_as_float(g & 0xffff0000u);
    asm("v_pk_fma_f32 %0, %1, %2, %3" : "=v"(acc) : "v"(v), "v"(dnp), "v"(acc));
}

// ---------- init: W -> fragment-packed split-bf16, zero bcursor/cnt/zero-row ----------
__global__ __launch_bounds__(512) void k_init(const float* __restrict__ W,
                                              unsigned short* __restrict__ wb_hi,
                                              unsigned short* __restrict__ wb_lo,
                                              int* __restrict__ bcursor,
                                              int* __restrict__ cnt_g,
                                              unsigned* __restrict__ zrow) {
    int tid = threadIdx.x;
    int g = blockIdx.x * 512 + tid;
    if (blockIdx.x == 0)
        for (int i = tid; i < NBUCK; i += 512) bcursor[i] = 0;
    if (blockIdx.x == 1 && tid < 64) zrow[tid] = 0;   // 256 B zero row
    for (int i = g; i < N_NODES + 1; i += PREPB * 512) cnt_g[i] = 0;

    int t = g;   // 0..32767
    int j = t & 7;
    int lane = (t >> 3) & 63;
    int s = (t >> 9) & 7;
    int nt = t >> 12;
    int k = s * 32 + (lane >> 4) * 8 + j;
    int n = nt * 16 + (lane & 15);
    float w = W[k * OUT_CH + n];
    unsigned short hi = f2bf(w);
    wb_hi[t] = hi;
    wb_lo[t] = f2bf(w - bf2f(hi));
}

// ---------- fused: single-pass bucket scatter (+ global degree count) || GEMM ----------
// Blocks 0..SCB-1: edge scatter into capacity-strided fine buckets (dst>>6);
// rank from LDS-histogram atomicAdd; also counts global in-degree cnt_g[dst]
// (L2-resident, no-return atomics) so downstream can compute dinv on the fly.
// Blocks SCB..: h = x @ W via split-bf16 MFMA, hbs = bf16(h) UNSCALED.
// LDS is a union: scatter uses lcnt/lbase (12.5 KB), gemm uses xbh/xbl (34.8 KB).
__global__ __launch_bounds__(512) void k_main(const int* __restrict__ rows,
                                              const int* __restrict__ cols,
                                              int* __restrict__ bcursor,
                                              int* __restrict__ cnt_g,
                                              unsigned* __restrict__ ebuf,
                                              const float* __restrict__ x,
                                              const unsigned short* __restrict__ wb_hi,
                                              const unsigned short* __restrict__ wb_lo,
                                              unsigned short* __restrict__ hbs) {
    __shared__ __align__(16) char smraw[34816];
    int t = threadIdx.x;

    if (blockIdx.x < SCB) {
        // ---- scatter path ----
        int* lcnt  = (int*)smraw;
        int* lbase = (int*)(smraw + 6272);
        for (int i = t; i < NBUCK; i += 512) lcnt[i] = 0;
        __syncthreads();

        int s0 = blockIdx.x * CSC;
        int e1 = min(N_EDGES, s0 + CSC);

        unsigned val[8];
        int bkr[8], rk[8];
#pragma unroll
        for (int u = 0; u < 8; ++u) {
            int i = s0 + t + u * 512;
            bool p = i < e1;
            int c = p ? cols[i] : 0;
            int r = p ? rows[i] : 0;
            int bk = c >> 6;
            bkr[u] = bk;
            val[u] = ((unsigned)(c & (BSZ - 1)) << 17) | (unsigned)r;
            rk[u] = p ? atomicAdd(&lcnt[bk], 1) : 0;
            if (p) atomicAdd(&cnt_g[c], 1);
        }
        __syncthreads();
        for (int i = t; i < NBUCK; i += 512) {
            int c2 = lcnt[i];
            lbase[i] = c2 ? atomicAdd(&bcursor[i], c2) : 0;
        }
        __syncthreads();
#pragma unroll
        for (int u = 0; u < 8; ++u) {
            int i = s0 + t + u * 512;
            if (i < e1) ebuf[bkr[u] * BCAP + lbase[bkr[u]] + rk[u]] = val[u];
        }
        return;
    }

    // ---- gemm path ----
    short8* xbh = (short8*)smraw;             // 1088 short8 = 17408 B
    short8* xbl = (short8*)(smraw + 17408);   // 1088 short8 = 17408 B
    int wv = t >> 6;        // 0..7 = n-tile
    int lane = t & 63;
    int row0 = (blockIdx.x - SCB) * GEMM_ROWS;

    short8 Bh[8], Bl[8];
    const short8* bhp = (const short8*)wb_hi + (size_t)wv * 8 * 64 + lane;
    const short8* blp = (const short8*)wb_lo + (size_t)wv * 8 * 64 + lane;
#pragma unroll
    for (int s = 0; s < 8; ++s) {
        Bh[s] = bhp[s * 64];
        Bl[s] = blp[s * 64];
    }

    // cooperative fp32 -> split-bf16 conversion, coalesced 1 KB-row loads
#pragma unroll
    for (int q = 0; q < 2; ++q) {
        int c = q * 512 + t;          // 0..1023
        int row = c >> 5;             // 0..31
        int cc  = c & 31;             // col chunk (8 floats)
        const float4* xp = (const float4*)(x + (size_t)(row0 + row) * IN_CH + cc * 8);
        float4 v0 = xp[0];
        float4 v1 = xp[1];
        float xv[8] = {v0.x, v0.y, v0.z, v0.w, v1.x, v1.y, v1.z, v1.w};
        short8 hh, ll;
#pragma unroll
        for (int j = 0; j < 8; ++j) {
            unsigned short hi = f2bf(xv[j]);
            hh[j] = (short)hi;
            ll[j] = (short)f2bf(xv[j] - bf2f(hi));
        }
        int ms = row >> 4, r15 = row & 15, s = cc >> 2, q2 = cc & 3;
        int idx = (ms * 8 + s) * 68 + q2 * 17 + r15;
        xbh[idx] = hh;
        xbl[idx] = ll;
    }
    __syncthreads();

    int r15 = lane & 15;
    int quad = lane >> 4;
    int lidx = quad * 17 + r15;

    floatx4 acc[2];
#pragma unroll
    for (int ms = 0; ms < 2; ++ms) {
        acc[ms] = (floatx4){0.f, 0.f, 0.f, 0.f};
#pragma unroll
        for (int s = 0; s < 8; ++s) {
            short8 ah = xbh[(ms * 8 + s) * 68 + lidx];
            short8 al = xbl[(ms * 8 + s) * 68 + lidx];
            acc[ms] = __builtin_amdgcn_mfma_f32_16x16x32_bf16(ah, Bh[s], acc[ms], 0, 0, 0);
            acc[ms] = __builtin_amdgcn_mfma_f32_16x16x32_bf16(ah, Bl[s], acc[ms], 0, 0, 0);
            acc[ms] = __builtin_amdgcn_mfma_f32_16x16x32_bf16(al, Bh[s], acc[ms], 0, 0, 0);
        }
    }

#pragma unroll
    for (int ms = 0; ms < 2; ++ms)
#pragma unroll
        for (int r = 0; r < 4; ++r) {
            int row = row0 + ms * 16 + quad * 4 + r;
            size_t idx = (size_t)row * OUT_CH + wv * 16 + r15;
            hbs[idx] = f2bf(acc[ms][r]);   // UNSCALED
        }
}

// ---------- fused: per-bucket sort (LDS) + gather-aggregate + scale + normalize ----------
// One block per fine bucket (64 nodes).  Phase 1: histogram (rank from
// atomicAdd) + 64-wide shfl scan + reorder edges into LDS es_l.  Phase 2:
// the proven 16-lane/node dwordx4 gather loop; dinv[src] computed on the fly
// from the globally-counted in-degree cnt_g[src] (L2-resident).
__global__ __launch_bounds__(512) void k_fin(const unsigned* __restrict__ ebuf,
                                             const int* __restrict__ bcursor,
                                             const int* __restrict__ cnt_g,
                                             const unsigned short* __restrict__ hbs,
                                             const float* __restrict__ b,
                                             float* __restrict__ out) {
    __shared__ int nh[BSZ];
    __shared__ int sb[BSZ];
    __shared__ int es_l[BCAP];
    int t = threadIdx.x;
    int bk = blockIdx.x;
    int bb = bk * BCAP;
    int bc = bcursor[bk];

    if (t < BSZ) nh[t] = 0;
    __syncthreads();

    unsigned val[3];
    int rk[3];
#pragma unroll
    for (int u = 0; u < 3; ++u) {
        int i = t + u * 512;
        bool p = i < bc;
        unsigned v = p ? ebuf[bb + i] : 0u;
        val[u] = v;
        rk[u] = p ? atomicAdd(&nh[v >> 17], 1) : 0;
    }
    __syncthreads();
    if (t < 64) {
        int s = nh[t];
#pragma unroll
        for (int d0 = 1; d0 < 64; d0 <<= 1) {
            int u = __shfl_up(s, d0, 64);
            if (t >= d0) s += u;
        }
        sb[t] = s - nh[t];   // exclusive base
    }
    __syncthreads();
#pragma unroll
    for (int u = 0; u < 3; ++u) {
        int i = t + u * 512;
        if (i < bc) {
            unsigned v = val[u];
            int dl = v >> 17;
            es_l[sb[dl] + rk[u]] = (int)(v & 0x1FFFFu) << 8;   // byte offset into hbs
        }
    }
    __syncthreads();

    // ---- phase 2: aggregate ----
    int lane = t & 63;
    int ll = lane & 15;
    int lane_byte = ll << 4;
    int bidx = (lane & 48) << 2;  // bpermute byte index of group's lane 0
    int grp = t >> 4;             // 0..31
    const char* hb = (const char*)hbs;
    const int zoff = N_NODES << 8;

    float4 bv0 = ((const float4*)b)[ll * 2];
    float4 bv1 = ((const float4*)b)[ll * 2 + 1];

    for (int r = 0; r < 2; ++r) {
        int dl = r * 32 + grp;
        int node = bk * BSZ + dl;
        if (node >= N_NODES) break;   // only last bucket, uniform across block

        int d  = nh[dl];
        int st0 = sb[dl];
        float dn = rsqrtf((float)(d + 1));

        uint4 gs = *(const uint4*)(hb + ((size_t)node << 8) + lane_byte);
        float2v dself; dself.x = dn; dself.y = dn;
        float2v acc[4];
#pragma unroll
        for (int c = 0; c < 4; ++c) { acc[c].x = 0.f; acc[c].y = 0.f; }
        pkfma(acc[0], gs.x, dself); pkfma(acc[1], gs.y, dself);
        pkfma(acc[2], gs.z, dself); pkfma(acc[3], gs.w, dself);

        int dm = d;
        dm = max(dm, __shfl_xor(dm, 16, 64));
        dm = max(dm, __shfl_xor(dm, 32, 64));
        int iters = __builtin_amdgcn_readfirstlane((dm + 15) >> 4);

        int off = zoff; float dnv = 0.f;
        if (ll < d) {
            off = es_l[st0 + ll];
            dnv = rsqrtf((float)(cnt_g[(unsigned)off >> 8] + 1));
        }

        for (int it = 0; it < iters; ++it) {
            int offn = zoff; float dnn = 0.f;
            int jb2 = (it + 1) << 4;
            if (jb2 + ll < d) {
                offn = es_l[st0 + jb2 + ll];
                dnn = rsqrtf((float)(cnt_g[(unsigned)offn >> 8] + 1));
            }
            int dni = __float_as_int(dnv);

            uint4 ga[4], gb[4];
            float2v da[4], db[4];
#pragma unroll
            for (int k = 0; k < 4; ++k) {
                int ro = __builtin_amdgcn_ds_bpermute(bidx + (k << 2), off);
                float f = __int_as_float(__builtin_amdgcn_ds_bpermute(bidx + (k << 2), dni));
                da[k].x = f; da[k].y = f;
                ga[k] = *(const uint4*)(hb + (unsigned)(ro + lane_byte));
            }
#pragma unroll
            for (int k = 0; k < 4; ++k) {
                int ro = __builtin_amdgcn_ds_bpermute(bidx + ((4 + k) << 2), off);
                float f = __int_as_float(__builtin_amdgcn_ds_bpermute(bidx + ((4 + k) << 2), dni));
                db[k].x = f; db[k].y = f;
                gb[k] = *(const uint4*)(hb + (unsigned)(ro + lane_byte));
            }
#pragma unroll
            for (int k = 0; k < 4; ++k) {
                pkfma(acc[0], ga[k].x, da[k]); pkfma(acc[1], ga[k].y, da[k]);
                pkfma(acc[2], ga[k].z, da[k]); pkfma(acc[3], ga[k].w, da[k]);
            }
#pragma unroll
            for (int k = 0; k < 4; ++k) {
                int ro = __builtin_amdgcn_ds_bpermute(bidx + ((8 + k) << 2), off);
                float f = __int_as_float(__builtin_amdgcn_ds_bpermute(bidx + ((8 + k) << 2), dni));
                da[k].x = f; da[k].y = f;
                ga[k] = *(const uint4*)(hb + (unsigned)(ro + lane_byte));
            }
#pragma unroll
            for (int k = 0; k < 4; ++k) {
                pkfma(acc[0], gb[k].x, db[k]); pkfma(acc[1], gb[k].y, db[k]);
                pkfma(acc[2], gb[k].z, db[k]); pkfma(acc[3], gb[k].w, db[k]);
            }
#pragma unroll
            for (int k = 0; k < 4; ++k) {
                int ro = __builtin_amdgcn_ds_bpermute(bidx + ((12 + k) << 2), off);
                float f = __int_as_float(__builtin_amdgcn_ds_bpermute(bidx + ((12 + k) << 2), dni));
                db[k].x = f; db[k].y = f;
                gb[k] = *(const uint4*)(hb + (unsigned)(ro + lane_byte));
            }
#pragma unroll
            for (int k = 0; k < 4; ++k) {
                pkfma(acc[0], ga[k].x, da[k]); pkfma(acc[1], ga[k].y, da[k]);
                pkfma(acc[2], ga[k].z, da[k]); pkfma(acc[3], ga[k].w, da[k]);
            }
#pragma unroll
            for (int k = 0; k < 4; ++k) {
                pkfma(acc[0], gb[k].x, db[k]); pkfma(acc[1], gb[k].y, db[k]);
                pkfma(acc[2], gb[k].z, db[k]); pkfma(acc[3], gb[k].w, db[k]);
            }

            off = offn; dnv = dnn;
        }

        float v[8];
        v[0] = dn * acc[0].x + bv0.x;  v[1] = dn * acc[0].y + bv0.y;
        v[2] = dn * acc[1].x + bv0.z;  v[3] = dn * acc[1].y + bv0.w;
        v[4] = dn * acc[2].x + bv1.x;  v[5] = dn * acc[2].y + bv1.y;
        v[6] = dn * acc[3].x + bv1.z;  v[7] = dn * acc[3].y + bv1.w;

        float lmin = v[0], lmax = v[0];
#pragma unroll
        for (int i = 1; i < 8; ++i) { lmin = fminf(lmin, v[i]); lmax = fmaxf(lmax, v[i]); }
#pragma unroll
        for (int m = 8; m; m >>= 1) {
            lmin = fminf(lmin, __shfl_xor(lmin, m, 64));
            lmax = fmaxf(lmax, __shfl_xor(lmax, m, 64));
        }
        float scale = 1.0f / (lmax - lmin);
        float z[8];
        float ss = 0.f;
#pragma unroll
        for (int i = 0; i < 8; ++i) { z[i] = (v[i] - lmin) * scale; ss += z[i] * z[i]; }
#pragma unroll
        for (int m = 8; m; m >>= 1) ss += __shfl_xor(ss, m, 64);
        float inv = 1.0f / fmaxf(sqrtf(ss), 1e-12f);

        float4 o0 = {z[0] * inv, z[1] * inv, z[2] * inv, z[3] * inv};
        float4 o1 = {z[4] * inv, z[5] * inv, z[6] * inv, z[7] * inv};
        float4* op = (float4*)(out + (size_t)node * OUT_CH);
        op[ll * 2] = o0;
        op[ll * 2 + 1] = o1;
    }
}

extern "C" void kernel_launch(void* const* d_in, const int* in_sizes, int n_in,
                              void* d_out, int out_size, void* d_ws, size_t ws_size,
                              hipStream_t stream) {
    const float* x = (const float*)d_in[0];        // fp32 [N, 256]
    const int* ei = (const int*)d_in[1];           // int32 [2, E]
    const float* W = (const float*)d_in[2];        // fp32 [256, 128]
    const float* b = (const float*)d_in[3];        // fp32 [128]
    float* out = (float*)d_out;                    // fp32 [N, 128]

    char* ws = (char*)d_ws;
    size_t o = 0;
    auto alloc = [&](size_t bytes) { void* p = ws + o; o = (o + bytes + 255) & ~(size_t)255; return p; };
    int*   bcursor = (int*)  alloc((size_t)NBUCK * 4);
    int*   cnt_g   = (int*)  alloc((size_t)(N_NODES + 1) * 4);
    unsigned short* wb_hi = (unsigned short*)alloc((size_t)IN_CH * OUT_CH * 2);
    unsigned short* wb_lo = (unsigned short*)alloc((size_t)IN_CH * OUT_CH * 2);
    unsigned short* hbs = (unsigned short*)alloc((size_t)(N_NODES + 1) * OUT_CH * 2);  // +1 zero row
    unsigned* ebuf = (unsigned*)alloc((size_t)NBUCK * BCAP * 4);

    const int* rows = ei;
    const int* cols = ei + N_EDGES;

    // init: W prep + zero bcursor/cnt_g/zero-row
    k_init<<<PREPB, 512, 0, stream>>>(W, wb_hi, wb_lo, bcursor, cnt_g,
                                      (unsigned*)(hbs + (size_t)N_NODES * OUT_CH));

    // fused: edge scatter (+ global degree count) || GEMM
    k_main<<<SCB + GEMB, 512, 0, stream>>>(rows, cols, bcursor, cnt_g, ebuf,
                                           x, wb_hi, wb_lo, hbs);

    // fused: per-bucket sort + aggregate + scale + normalize
    k_fin<<<NBUCK, 512, 0, stream>>>(ebuf, bcursor, cnt_g, hbs, b, out);
}

// Round 8
// 314.044 us; speedup vs baseline: 1.0180x; 1.0180x over previous
//
#include <hip/hip_runtime.h>
#include <hip/hip_bf16.h>

#define N_NODES 100000
#define N_EDGES 1600000
#define IN_CH 256
#define OUT_CH 128

#define BSZ 256            // nodes per bucket (power of 2)
#define NBUCK 391          // ceil(N_NODES / BSZ)
#define BCAP 4736          // bucket capacity: mean 4092, sd ~64 -> 10 sigma headroom
#define CSC 4096           // edges per block, scatter
#define SCB 391            // scatter blocks = ceil(N_EDGES / CSC)
#define PREPB 64           // init blocks (64 x 512 = 32768 W elements)

#define GEMM_ROWS 32       // rows per gemm block
#define GEMB 3125          // N_NODES / GEMM_ROWS

typedef __attribute__((ext_vector_type(8))) short short8;
typedef __attribute__((ext_vector_type(4))) float floatx4;
typedef __attribute__((ext_vector_type(2))) float float2v;

union bfu { __hip_bfloat16 b; unsigned short u; };

__device__ inline unsigned short f2bf(float v) {
    bfu cv; cv.b = __float2bfloat16(v); return cv.u;
}
__device__ inline float bf2f(unsigned short u) {
    bfu cv; cv.u = u; return __bfloat162float(cv.b);
}

// acc += dnp * unpacked(g): one v_pk_fma_f32 for both channels
__device__ inline void pkfma(float2v& acc, unsigned g, float2v dnp) {
    float2v v;
    v.x = __uint_as_float(g << 16);
    v.y = __uint_as_float(g & 0xffff0000u);
    asm("v_pk_fma_f32 %0, %1, %2, %3" : "=v"(acc) : "v"(v), "v"(dnp), "v"(acc));
}

// ---------- init: W -> fragment-packed split-bf16, zero bcursor/cnt_g/zero-row ----------
__global__ __launch_bounds__(512) void k_init(const float* __restrict__ W,
                                              unsigned short* __restrict__ wb_hi,
                                              unsigned short* __restrict__ wb_lo,
                                              int* __restrict__ bcursor,
                                              int* __restrict__ cnt_g,
                                              unsigned* __restrict__ zrow) {
    int tid = threadIdx.x;
    int g = blockIdx.x * 512 + tid;
    if (blockIdx.x == 0 && tid < NBUCK) bcursor[tid] = 0;
    if (blockIdx.x == 1 && tid < 64) zrow[tid] = 0;   // 256 B zero row
    for (int i = g; i < N_NODES + 1; i += PREPB * 512) cnt_g[i] = 0;

    int t = g;   // 0..32767
    int j = t & 7;
    int lane = (t >> 3) & 63;
    int s = (t >> 9) & 7;
    int nt = t >> 12;
    int k = s * 32 + (lane >> 4) * 8 + j;
    int n = nt * 16 + (lane & 15);
    float w = W[k * OUT_CH + n];
    unsigned short hi = f2bf(w);
    wb_hi[t] = hi;
    wb_lo[t] = f2bf(w - bf2f(hi));
}

// ---------- fused: coarse bucket scatter (+ global degree count) || GEMM ----------
// Blocks 0..SCB-1: edge scatter into capacity-strided COARSE buckets (dst>>8):
// each block writes ~10.5 edges per bucket contiguously (write-coalesced --
// R7's fine buckets fragmented writes, WRITE_SIZE 37->93 MB).  Also counts
// global in-degree cnt_g[dst] (L2-resident, no-return atomics).
// Blocks SCB..: h = x @ W via split-bf16 MFMA, hbs = bf16(h) UNSCALED.
__global__ __launch_bounds__(512) void k_main(const int* __restrict__ rows,
                                              const int* __restrict__ cols,
                                              int* __restrict__ bcursor,
                                              int* __restrict__ cnt_g,
                                              unsigned* __restrict__ ebuf,
                                              const float* __restrict__ x,
                                              const unsigned short* __restrict__ wb_hi,
                                              const unsigned short* __restrict__ wb_lo,
                                              unsigned short* __restrict__ hbs) {
    __shared__ int lcnt[NBUCK];
    __shared__ int lbase[NBUCK];
    __shared__ short8 xbh[2 * 8 * 68];   // 17408 B
    __shared__ short8 xbl[2 * 8 * 68];   // 17408 B
    int t = threadIdx.x;

    if (blockIdx.x < SCB) {
        // ---- scatter path ----
        if (t < NBUCK) lcnt[t] = 0;
        __syncthreads();

        int s0 = blockIdx.x * CSC;
        int e1 = min(N_EDGES, s0 + CSC);

        unsigned val[8];
        int bkr[8], rk[8];
#pragma unroll
        for (int u = 0; u < 8; ++u) {
            int i = s0 + t + u * 512;
            bool p = i < e1;
            int c = p ? cols[i] : 0;
            int r = p ? rows[i] : 0;
            int bk = c >> 8;
            bkr[u] = bk;
            val[u] = ((unsigned)(c & (BSZ - 1)) << 17) | (unsigned)r;
            rk[u] = p ? atomicAdd(&lcnt[bk], 1) : 0;
            if (p) atomicAdd(&cnt_g[c], 1);
        }
        __syncthreads();
        if (t < NBUCK) {
            int c2 = lcnt[t];
            lbase[t] = c2 ? atomicAdd(&bcursor[t], c2) : 0;
        }
        __syncthreads();
#pragma unroll
        for (int u = 0; u < 8; ++u) {
            int i = s0 + t + u * 512;
            if (i < e1) ebuf[bkr[u] * BCAP + lbase[bkr[u]] + rk[u]] = val[u];
        }
        return;
    }

    // ---- gemm path ----
    int wv = t >> 6;        // 0..7 = n-tile
    int lane = t & 63;
    int row0 = (blockIdx.x - SCB) * GEMM_ROWS;

    short8 Bh[8], Bl[8];
    const short8* bhp = (const short8*)wb_hi + (size_t)wv * 8 * 64 + lane;
    const short8* blp = (const short8*)wb_lo + (size_t)wv * 8 * 64 + lane;
#pragma unroll
    for (int s = 0; s < 8; ++s) {
        Bh[s] = bhp[s * 64];
        Bl[s] = blp[s * 64];
    }

    // cooperative fp32 -> split-bf16 conversion, coalesced 1 KB-row loads
#pragma unroll
    for (int q = 0; q < 2; ++q) {
        int c = q * 512 + t;          // 0..1023
        int row = c >> 5;             // 0..31
        int cc  = c & 31;             // col chunk (8 floats)
        const float4* xp = (const float4*)(x + (size_t)(row0 + row) * IN_CH + cc * 8);
        float4 v0 = xp[0];
        float4 v1 = xp[1];
        float xv[8] = {v0.x, v0.y, v0.z, v0.w, v1.x, v1.y, v1.z, v1.w};
        short8 hh, ll;
#pragma unroll
        for (int j = 0; j < 8; ++j) {
            unsigned short hi = f2bf(xv[j]);
            hh[j] = (short)hi;
            ll[j] = (short)f2bf(xv[j] - bf2f(hi));
        }
        int ms = row >> 4, r15 = row & 15, s = cc >> 2, q2 = cc & 3;
        int idx = (ms * 8 + s) * 68 + q2 * 17 + r15;
        xbh[idx] = hh;
        xbl[idx] = ll;
    }
    __syncthreads();

    int r15 = lane & 15;
    int quad = lane >> 4;
    int lidx = quad * 17 + r15;

    floatx4 acc[2];
#pragma unroll
    for (int ms = 0; ms < 2; ++ms) {
        acc[ms] = (floatx4){0.f, 0.f, 0.f, 0.f};
#pragma unroll
        for (int s = 0; s < 8; ++s) {
            short8 ah = xbh[(ms * 8 + s) * 68 + lidx];
            short8 al = xbl[(ms * 8 + s) * 68 + lidx];
            acc[ms] = __builtin_amdgcn_mfma_f32_16x16x32_bf16(ah, Bh[s], acc[ms], 0, 0, 0);
            acc[ms] = __builtin_amdgcn_mfma_f32_16x16x32_bf16(ah, Bl[s], acc[ms], 0, 0, 0);
            acc[ms] = __builtin_amdgcn_mfma_f32_16x16x32_bf16(al, Bh[s], acc[ms], 0, 0, 0);
        }
    }

#pragma unroll
    for (int ms = 0; ms < 2; ++ms)
#pragma unroll
        for (int r = 0; r < 4; ++r) {
            int row = row0 + ms * 16 + quad * 4 + r;
            size_t idx = (size_t)row * OUT_CH + wv * 16 + r15;
            hbs[idx] = f2bf(acc[ms][r]);   // UNSCALED
        }
}

// ---------- fused: per-coarse-bucket sort (LDS) + gather-aggregate + finish ----------
// One block per coarse bucket (256 nodes, ~4096 edges).  Phase 1: LDS
// histogram (rank from atomicAdd) + 8-round scan + reorder edges into es_l
// (19 KB LDS).  In-bucket count == full in-degree (buckets partition by dst).
// Phase 2: 32 groups x 8 rounds of the proven 16-lane/dwordx4 gather;
// dinv[src] from rsqrt(cnt_g[src]+1) (L2-resident).  Last-bucket lanes are
// predicated (act), never skipped, so wave-uniform shuffles stay defined.
__global__ __launch_bounds__(512) void k_fin(const unsigned* __restrict__ ebuf,
                                             const int* __restrict__ bcursor,
                                             const int* __restrict__ cnt_g,
                                             const unsigned short* __restrict__ hbs,
                                             const float* __restrict__ b,
                                             float* __restrict__ out) {
    __shared__ int nh[BSZ];
    __shared__ int sc[BSZ];
    __shared__ int es_l[BCAP];
    int t = threadIdx.x;
    int bk = blockIdx.x;
    int bb = bk * BCAP;
    int bc = bcursor[bk];

    if (t < BSZ) nh[t] = 0;
    __syncthreads();

    unsigned val[10];
    int rk[10];
#pragma unroll
    for (int u = 0; u < 10; ++u) {
        int i = t + u * 512;
        bool p = i < bc;
        unsigned v = p ? ebuf[bb + i] : 0u;
        val[u] = v;
        rk[u] = p ? atomicAdd(&nh[v >> 17], 1) : 0;
    }
    __syncthreads();
    if (t < BSZ) sc[t] = nh[t];
    __syncthreads();
    for (int off = 1; off < BSZ; off <<= 1) {
        int v = (t < BSZ && t >= off) ? sc[t - off] : 0;
        __syncthreads();
        if (t < BSZ) sc[t] += v;
        __syncthreads();
    }
#pragma unroll
    for (int u = 0; u < 10; ++u) {
        int i = t + u * 512;
        if (i < bc) {
            unsigned v = val[u];
            int dl = v >> 17;
            es_l[sc[dl] - nh[dl] + rk[u]] = (int)(v & 0x1FFFFu) << 8;   // byte offset into hbs
        }
    }
    __syncthreads();

    // ---- phase 2: aggregate 256 nodes (32 groups x 8 rounds) ----
    int lane = t & 63;
    int ll = lane & 15;
    int lane_byte = ll << 4;
    int bidx = (lane & 48) << 2;  // bpermute byte index of group's lane 0
    int grp = t >> 4;             // 0..31
    const char* hb = (const char*)hbs;
    const int zoff = N_NODES << 8;

    float4 bv0 = ((const float4*)b)[ll * 2];
    float4 bv1 = ((const float4*)b)[ll * 2 + 1];

    for (int r = 0; r < 8; ++r) {
        int dl = r * 32 + grp;
        int node = bk * BSZ + dl;
        bool act = node < N_NODES;          // group-uniform

        int d   = act ? nh[dl] : 0;
        int st0 = act ? (sc[dl] - nh[dl]) : 0;
        float dn = rsqrtf((float)(d + 1));
        int nrow = act ? node : N_NODES;    // inactive groups read the zero row

        uint4 gs = *(const uint4*)(hb + ((size_t)nrow << 8) + lane_byte);
        float2v dself; dself.x = dn; dself.y = dn;
        float2v acc[4];
#pragma unroll
        for (int c = 0; c < 4; ++c) { acc[c].x = 0.f; acc[c].y = 0.f; }
        pkfma(acc[0], gs.x, dself); pkfma(acc[1], gs.y, dself);
        pkfma(acc[2], gs.z, dself); pkfma(acc[3], gs.w, dself);

        int dm = d;
        dm = max(dm, __shfl_xor(dm, 16, 64));
        dm = max(dm, __shfl_xor(dm, 32, 64));
        int iters = __builtin_amdgcn_readfirstlane((dm + 15) >> 4);

        int off = zoff; float dnv = 0.f;
        if (ll < d) {
            off = es_l[st0 + ll];
            dnv = rsqrtf((float)(cnt_g[(unsigned)off >> 8] + 1));
        }

        for (int it = 0; it < iters; ++it) {
            int offn = zoff; float dnn = 0.f;
            int jb2 = (it + 1) << 4;
            if (jb2 + ll < d) {
                offn = es_l[st0 + jb2 + ll];
                dnn = rsqrtf((float)(cnt_g[(unsigned)offn >> 8] + 1));
            }
            int dni = __float_as_int(dnv);

            uint4 ga[4], gb[4];
            float2v da[4], db[4];
#pragma unroll
            for (int k = 0; k < 4; ++k) {
                int ro = __builtin_amdgcn_ds_bpermute(bidx + (k << 2), off);
                float f = __int_as_float(__builtin_amdgcn_ds_bpermute(bidx + (k << 2), dni));
                da[k].x = f; da[k].y = f;
                ga[k] = *(const uint4*)(hb + (unsigned)(ro + lane_byte));
            }
#pragma unroll
            for (int k = 0; k < 4; ++k) {
                int ro = __builtin_amdgcn_ds_bpermute(bidx + ((4 + k) << 2), off);
                float f = __int_as_float(__builtin_amdgcn_ds_bpermute(bidx + ((4 + k) << 2), dni));
                db[k].x = f; db[k].y = f;
                gb[k] = *(const uint4*)(hb + (unsigned)(ro + lane_byte));
            }
#pragma unroll
            for (int k = 0; k < 4; ++k) {
                pkfma(acc[0], ga[k].x, da[k]); pkfma(acc[1], ga[k].y, da[k]);
                pkfma(acc[2], ga[k].z, da[k]); pkfma(acc[3], ga[k].w, da[k]);
            }
#pragma unroll
            for (int k = 0; k < 4; ++k) {
                int ro = __builtin_amdgcn_ds_bpermute(bidx + ((8 + k) << 2), off);
                float f = __int_as_float(__builtin_amdgcn_ds_bpermute(bidx + ((8 + k) << 2), dni));
                da[k].x = f; da[k].y = f;
                ga[k] = *(const uint4*)(hb + (unsigned)(ro + lane_byte));
            }
#pragma unroll
            for (int k = 0; k < 4; ++k) {
                pkfma(acc[0], gb[k].x, db[k]); pkfma(acc[1], gb[k].y, db[k]);
                pkfma(acc[2], gb[k].z, db[k]); pkfma(acc[3], gb[k].w, db[k]);
            }
#pragma unroll
            for (int k = 0; k < 4; ++k) {
                int ro = __builtin_amdgcn_ds_bpermute(bidx + ((12 + k) << 2), off);
                float f = __int_as_float(__builtin_amdgcn_ds_bpermute(bidx + ((12 + k) << 2), dni));
                db[k].x = f; db[k].y = f;
                gb[k] = *(const uint4*)(hb + (unsigned)(ro + lane_byte));
            }
#pragma unroll
            for (int k = 0; k < 4; ++k) {
                pkfma(acc[0], ga[k].x, da[k]); pkfma(acc[1], ga[k].y, da[k]);
                pkfma(acc[2], ga[k].z, da[k]); pkfma(acc[3], ga[k].w, da[k]);
            }
#pragma unroll
            for (int k = 0; k < 4; ++k) {
                pkfma(acc[0], gb[k].x, db[k]); pkfma(acc[1], gb[k].y, db[k]);
                pkfma(acc[2], gb[k].z, db[k]); pkfma(acc[3], gb[k].w, db[k]);
            }

            off = offn; dnv = dnn;
        }

        float v[8];
        v[0] = dn * acc[0].x + bv0.x;  v[1] = dn * acc[0].y + bv0.y;
        v[2] = dn * acc[1].x + bv0.z;  v[3] = dn * acc[1].y + bv0.w;
        v[4] = dn * acc[2].x + bv1.x;  v[5] = dn * acc[2].y + bv1.y;
        v[6] = dn * acc[3].x + bv1.z;  v[7] = dn * acc[3].y + bv1.w;

        float lmin = v[0], lmax = v[0];
#pragma unroll
        for (int i = 1; i < 8; ++i) { lmin = fminf(lmin, v[i]); lmax = fmaxf(lmax, v[i]); }
#pragma unroll
        for (int m = 8; m; m >>= 1) {
            lmin = fminf(lmin, __shfl_xor(lmin, m, 64));
            lmax = fmaxf(lmax, __shfl_xor(lmax, m, 64));
        }
        float scale = 1.0f / (lmax - lmin);
        float z[8];
        float ss = 0.f;
#pragma unroll
        for (int i = 0; i < 8; ++i) { z[i] = (v[i] - lmin) * scale; ss += z[i] * z[i]; }
#pragma unroll
        for (int m = 8; m; m >>= 1) ss += __shfl_xor(ss, m, 64);
        float inv = 1.0f / fmaxf(sqrtf(ss), 1e-12f);

        if (act) {
            float4 o0 = {z[0] * inv, z[1] * inv, z[2] * inv, z[3] * inv};
            float4 o1 = {z[4] * inv, z[5] * inv, z[6] * inv, z[7] * inv};
            float4* op = (float4*)(out + (size_t)node * OUT_CH);
            op[ll * 2] = o0;
            op[ll * 2 + 1] = o1;
        }
    }
}

extern "C" void kernel_launch(void* const* d_in, const int* in_sizes, int n_in,
                              void* d_out, int out_size, void* d_ws, size_t ws_size,
                              hipStream_t stream) {
    const float* x = (const float*)d_in[0];        // fp32 [N, 256]
    const int* ei = (const int*)d_in[1];           // int32 [2, E]
    const float* W = (const float*)d_in[2];        // fp32 [256, 128]
    const float* b = (const float*)d_in[3];        // fp32 [128]
    float* out = (float*)d_out;                    // fp32 [N, 128]

    char* ws = (char*)d_ws;
    size_t o = 0;
    auto alloc = [&](size_t bytes) { void* p = ws + o; o = (o + bytes + 255) & ~(size_t)255; return p; };
    int*   bcursor = (int*)  alloc((size_t)NBUCK * 4);
    int*   cnt_g   = (int*)  alloc((size_t)(N_NODES + 1) * 4);
    unsigned short* wb_hi = (unsigned short*)alloc((size_t)IN_CH * OUT_CH * 2);
    unsigned short* wb_lo = (unsigned short*)alloc((size_t)IN_CH * OUT_CH * 2);
    unsigned short* hbs = (unsigned short*)alloc((size_t)(N_NODES + 1) * OUT_CH * 2);  // +1 zero row
    unsigned* ebuf = (unsigned*)alloc((size_t)NBUCK * BCAP * 4);

    const int* rows = ei;
    const int* cols = ei + N_EDGES;

    // init: W prep + zero bcursor/cnt_g/zero-row
    k_init<<<PREPB, 512, 0, stream>>>(W, wb_hi, wb_lo, bcursor, cnt_g,
                                      (unsigned*)(hbs + (size_t)N_NODES * OUT_CH));

    // fused: coarse edge scatter (+ global degree count) || GEMM
    k_main<<<SCB + GEMB, 512, 0, stream>>>(rows, cols, bcursor, cnt_g, ebuf,
                                           x, wb_hi, wb_lo, hbs);

    // fused: per-bucket sort + aggregate + scale + normalize
    k_fin<<<NBUCK, 512, 0, stream>>>(ebuf, bcursor, cnt_g, hbs, b, out);
}

// Round 9
// 270.390 us; speedup vs baseline: 1.1823x; 1.1614x over previous
//
#include <hip/hip_runtime.h>
#include <hip/hip_bf16.h>

#define N_NODES 100000
#define N_EDGES 1600000
#define IN_CH 256
#define OUT_CH 128

#define BSZ 256            // nodes per bucket (power of 2)
#define NBUCK 391          // ceil(N_NODES / BSZ)
#define BCAP 4736          // bucket capacity: mean 4092, sd ~64 -> 10 sigma headroom
#define CSC 4096           // edges per block, scatter
#define SCB 391            // scatter blocks = ceil(N_EDGES / CSC)
#define PREPB 64           // init blocks (64 x 512 = 32768 W elements)

#define GEMM_ROWS 32       // rows per gemm block
#define GEMMA 1024         // gemm blocks in launch A (rows 0..32767)
#define GEMMB 2101         // gemm blocks in launch B (rows 32768..99999)

typedef __attribute__((ext_vector_type(8))) short short8;
typedef __attribute__((ext_vector_type(4))) float floatx4;
typedef __attribute__((ext_vector_type(2))) float float2v;

union bfu { __hip_bfloat16 b; unsigned short u; };

__device__ inline unsigned short f2bf(float v) {
    bfu cv; cv.b = __float2bfloat16(v); return cv.u;
}
__device__ inline float bf2f(unsigned short u) {
    bfu cv; cv.u = u; return __bfloat162float(cv.b);
}

// acc += dnp * unpacked(g): one v_pk_fma_f32 for both channels
__device__ inline void pkfma(float2v& acc, unsigned g, float2v dnp) {
    float2v v;
    v.x = __uint_as_float(g << 16);
    v.y = __uint_as_float(g & 0xffff0000u);
    asm("v_pk_fma_f32 %0, %1, %2, %3" : "=v"(acc) : "v"(v), "v"(dnp), "v"(acc));
}

// ---------- shared gemm body: 32 rows, split-bf16 MFMA, padded LDS ----------
__device__ inline void gemm_body(const float* __restrict__ x,
                                 const unsigned short* __restrict__ wb_hi,
                                 const unsigned short* __restrict__ wb_lo,
                                 unsigned short* __restrict__ hbs,
                                 int row0, int t, short8* xbh, short8* xbl) {
    int wv = t >> 6;        // 0..7 = n-tile
    int lane = t & 63;

    short8 Bh[8], Bl[8];
    const short8* bhp = (const short8*)wb_hi + (size_t)wv * 8 * 64 + lane;
    const short8* blp = (const short8*)wb_lo + (size_t)wv * 8 * 64 + lane;
#pragma unroll
    for (int s = 0; s < 8; ++s) {
        Bh[s] = bhp[s * 64];
        Bl[s] = blp[s * 64];
    }

    // cooperative fp32 -> split-bf16 conversion, coalesced 1 KB-row loads
#pragma unroll
    for (int q = 0; q < 2; ++q) {
        int c = q * 512 + t;          // 0..1023
        int row = c >> 5;             // 0..31
        int cc  = c & 31;             // col chunk (8 floats)
        const float4* xp = (const float4*)(x + (size_t)(row0 + row) * IN_CH + cc * 8);
        float4 v0 = xp[0];
        float4 v1 = xp[1];
        float xv[8] = {v0.x, v0.y, v0.z, v0.w, v1.x, v1.y, v1.z, v1.w};
        short8 hh, ll;
#pragma unroll
        for (int j = 0; j < 8; ++j) {
            unsigned short hi = f2bf(xv[j]);
            hh[j] = (short)hi;
            ll[j] = (short)f2bf(xv[j] - bf2f(hi));
        }
        int ms = row >> 4, r15 = row & 15, s = cc >> 2, q2 = cc & 3;
        int idx = (ms * 8 + s) * 68 + q2 * 17 + r15;
        xbh[idx] = hh;
        xbl[idx] = ll;
    }
    __syncthreads();

    int r15 = lane & 15;
    int quad = lane >> 4;
    int lidx = quad * 17 + r15;

    floatx4 acc[2];
#pragma unroll
    for (int ms = 0; ms < 2; ++ms) {
        acc[ms] = (floatx4){0.f, 0.f, 0.f, 0.f};
#pragma unroll
        for (int s = 0; s < 8; ++s) {
            short8 ah = xbh[(ms * 8 + s) * 68 + lidx];
            short8 al = xbl[(ms * 8 + s) * 68 + lidx];
            acc[ms] = __builtin_amdgcn_mfma_f32_16x16x32_bf16(ah, Bh[s], acc[ms], 0, 0, 0);
            acc[ms] = __builtin_amdgcn_mfma_f32_16x16x32_bf16(ah, Bl[s], acc[ms], 0, 0, 0);
            acc[ms] = __builtin_amdgcn_mfma_f32_16x16x32_bf16(al, Bh[s], acc[ms], 0, 0, 0);
        }
    }

#pragma unroll
    for (int ms = 0; ms < 2; ++ms)
#pragma unroll
        for (int r = 0; r < 4; ++r) {
            int row = row0 + ms * 16 + quad * 4 + r;
            size_t idx = (size_t)row * OUT_CH + wv * 16 + r15;
            hbs[idx] = f2bf(acc[ms][r]);   // UNSCALED
        }
}

// ---------- init: W -> fragment-packed split-bf16, zero bcursor + zero-row ----------
__global__ __launch_bounds__(512) void k_init(const float* __restrict__ W,
                                              unsigned short* __restrict__ wb_hi,
                                              unsigned short* __restrict__ wb_lo,
                                              int* __restrict__ bcursor,
                                              unsigned* __restrict__ zrow) {
    int tid = threadIdx.x;
    if (blockIdx.x == 0 && tid < NBUCK) bcursor[tid] = 0;
    if (blockIdx.x == 1 && tid < 64) zrow[tid] = 0;   // 256 B zero row

    int t = blockIdx.x * 512 + tid;   // 0..32767
    int j = t & 7;
    int lane = (t >> 3) & 63;
    int s = (t >> 9) & 7;
    int nt = t >> 12;
    int k = s * 32 + (lane >> 4) * 8 + j;
    int n = nt * 16 + (lane & 15);
    float w = W[k * OUT_CH + n];
    unsigned short hi = f2bf(w);
    wb_hi[t] = hi;
    wb_lo[t] = f2bf(w - bf2f(hi));
}

// ---------- launch A: coarse bucket scatter || gemm rows 0..32767 ----------
// NO per-edge global atomics (R8 lesson: cnt_g atomicAdds cost +48 MB writes,
// +46 us).  Degrees come from pb_build's in-bucket histogram (launch B).
__global__ __launch_bounds__(512) void k_mainA(const int* __restrict__ rows,
                                               const int* __restrict__ cols,
                                               int* __restrict__ bcursor,
                                               unsigned* __restrict__ ebuf,
                                               const float* __restrict__ x,
                                               const unsigned short* __restrict__ wb_hi,
                                               const unsigned short* __restrict__ wb_lo,
                                               unsigned short* __restrict__ hbs) {
    __shared__ int lcnt[NBUCK];
    __shared__ int lbase[NBUCK];
    __shared__ short8 xbh[2 * 8 * 68];   // 17408 B
    __shared__ short8 xbl[2 * 8 * 68];   // 17408 B
    int t = threadIdx.x;

    if (blockIdx.x < SCB) {
        // ---- scatter path (R6-proven) ----
        if (t < NBUCK) lcnt[t] = 0;
        __syncthreads();

        int s0 = blockIdx.x * CSC;
        int e1 = min(N_EDGES, s0 + CSC);

        unsigned val[8];
        int bkr[8], rk[8];
#pragma unroll
        for (int u = 0; u < 8; ++u) {
            int i = s0 + t + u * 512;
            bool p = i < e1;
            int c = p ? cols[i] : 0;
            int r = p ? rows[i] : 0;
            int bk = c >> 8;
            bkr[u] = bk;
            val[u] = ((unsigned)(c & (BSZ - 1)) << 17) | (unsigned)r;
            rk[u] = p ? atomicAdd(&lcnt[bk], 1) : 0;
        }
        __syncthreads();
        if (t < NBUCK) {
            int c2 = lcnt[t];
            lbase[t] = c2 ? atomicAdd(&bcursor[t], c2) : 0;
        }
        __syncthreads();
#pragma unroll
        for (int u = 0; u < 8; ++u) {
            int i = s0 + t + u * 512;
            if (i < e1) ebuf[bkr[u] * BCAP + lbase[bkr[u]] + rk[u]] = val[u];
        }
        return;
    }

    gemm_body(x, wb_hi, wb_lo, hbs, (int)(blockIdx.x - SCB) * GEMM_ROWS, t, xbh, xbl);
}

// ---------- launch B: pb_build || gemm rows 32768..99999 ----------
// pb's latency-bound blocks (391, 1.5/CU alone) co-reside with gemm's
// MFMA-heavy blocks -> pb hides under gemm (m114 overlap).
__global__ __launch_bounds__(512) void k_mainB(const unsigned* __restrict__ ebuf,
                                               const int* __restrict__ bcursor,
                                               int* __restrict__ cnt,
                                               int* __restrict__ base,
                                               float* __restrict__ dinv,
                                               int* __restrict__ es,
                                               const float* __restrict__ x,
                                               const unsigned short* __restrict__ wb_hi,
                                               const unsigned short* __restrict__ wb_lo,
                                               unsigned short* __restrict__ hbs) {
    __shared__ int nh[BSZ];
    __shared__ int sc[BSZ];
    __shared__ short8 xbh[2 * 8 * 68];
    __shared__ short8 xbl[2 * 8 * 68];
    int t = threadIdx.x;

    if (blockIdx.x < NBUCK) {
        // ---- pb path (R6-proven): single edge pass, rank from histogram atomic ----
        int bk = blockIdx.x;
        int bb = bk * BCAP;
        int bc = bcursor[bk];
        if (t < BSZ) nh[t] = 0;
        __syncthreads();

        unsigned val[10];
        int rk[10];
#pragma unroll
        for (int u = 0; u < 10; ++u) {
            int i = t + u * 512;
            bool p = i < bc;
            unsigned v = p ? ebuf[bb + i] : 0u;
            val[u] = v;
            rk[u] = p ? atomicAdd(&nh[v >> 17], 1) : 0;
        }
        __syncthreads();
        if (t < BSZ) sc[t] = nh[t];
        __syncthreads();
        for (int off = 1; off < BSZ; off <<= 1) {
            int v = (t < BSZ && t >= off) ? sc[t - off] : 0;
            __syncthreads();
            if (t < BSZ) sc[t] += v;
            __syncthreads();
        }
        if (t < BSZ) {
            int node = bk * BSZ + t;
            if (node < N_NODES) {
                int c = nh[t];
                cnt[node] = c;
                base[node] = bb + sc[t] - c;
                dinv[node] = rsqrtf((float)(c + 1));
            }
        }
#pragma unroll
        for (int u = 0; u < 10; ++u) {
            int i = t + u * 512;
            if (i < bc) {
                unsigned v = val[u];
                int dl = v >> 17;
                es[bb + sc[dl] - nh[dl] + rk[u]] = (int)(v & 0x1FFFFu) << 8;  // byte offset
            }
        }
        return;
    }

    gemm_body(x, wb_hi, wb_lo, hbs,
              32768 + (int)(blockIdx.x - NBUCK) * GEMM_ROWS, t, xbh, xbl);
}

// ---------- fused gather-aggregate + minmax scale + L2 normalize (R6-proven) ----------
// 4 nodes per wave, 16 lanes per node, dwordx4 gathers; per-edge dinv[src]
// gathered (L2-resident 400 KB) with 1-iteration prefetch, broadcast via the
// same ds_bpermute as the row offset, applied with v_pk_fma.
__global__ __launch_bounds__(256) void k_agg_fin(const unsigned short* __restrict__ hbs,
                                                 const float* __restrict__ dinv,
                                                 const int* __restrict__ es,
                                                 const int* __restrict__ base,
                                                 const int* __restrict__ cnt,
                                                 const float* __restrict__ b,
                                                 float* __restrict__ out) {
    int t = threadIdx.x;
    int lane = t & 63;
    int ll = lane & 15;           // lane within node group
    int node = blockIdx.x * 16 + (t >> 4);

    const char* hb = (const char*)hbs;
    const char* dvc = (const char*)dinv;
    int lane_byte = ll << 4;
    int bidx = (lane & 48) << 2;  // bpermute byte index of group's lane 0

    float dn = dinv[node];
    int d  = cnt[node];
    int st = base[node];

    float4 bv0 = ((const float4*)b)[ll * 2];
    float4 bv1 = ((const float4*)b)[ll * 2 + 1];

    // self row: dn * h_self (outer dn applied at end -> dn^2 h_self)
    uint4 gs = *(const uint4*)(hb + ((size_t)node << 8) + lane_byte);
    float2v dself; dself.x = dn; dself.y = dn;
    float2v acc[4];
#pragma unroll
    for (int c = 0; c < 4; ++c) { acc[c].x = 0.f; acc[c].y = 0.f; }
    pkfma(acc[0], gs.x, dself); pkfma(acc[1], gs.y, dself);
    pkfma(acc[2], gs.z, dself); pkfma(acc[3], gs.w, dself);

    int dm = d;
    dm = max(dm, __shfl_xor(dm, 16, 64));
    dm = max(dm, __shfl_xor(dm, 32, 64));
    int iters = __builtin_amdgcn_readfirstlane((dm + 15) >> 4);

    const int zoff = N_NODES << 8;   // zero row byte offset

    // preload iter 0's edge offsets + source dinv
    int off = zoff; float dnv = 0.f;
    if (ll < d) {
        off = es[st + ll];
        dnv = *(const float*)(dvc + ((unsigned)off >> 6));   // dinv[src]
    }

    for (int it = 0; it < iters; ++it) {
        int offn = zoff; float dnn = 0.f;
        int jb2 = (it + 1) << 4;
        if (jb2 + ll < d) {
            offn = es[st + jb2 + ll];
            dnn = *(const float*)(dvc + ((unsigned)offn >> 6));
        }
        int dni = __float_as_int(dnv);

        uint4 ga[4], gb[4];
        float2v da[4], db[4];
#pragma unroll
        for (int k = 0; k < 4; ++k) {
            int ro = __builtin_amdgcn_ds_bpermute(bidx + (k << 2), off);
            float f = __int_as_float(__builtin_amdgcn_ds_bpermute(bidx + (k << 2), dni));
            da[k].x = f; da[k].y = f;
            ga[k] = *(const uint4*)(hb + (unsigned)(ro + lane_byte));
        }
#pragma unroll
        for (int k = 0; k < 4; ++k) {
            int ro = __builtin_amdgcn_ds_bpermute(bidx + ((4 + k) << 2), off);
            float f = __int_as_float(__builtin_amdgcn_ds_bpermute(bidx + ((4 + k) << 2), dni));
            db[k].x = f; db[k].y = f;
            gb[k] = *(const uint4*)(hb + (unsigned)(ro + lane_byte));
        }
#pragma unroll
        for (int k = 0; k < 4; ++k) {
            pkfma(acc[0], ga[k].x, da[k]); pkfma(acc[1], ga[k].y, da[k]);
            pkfma(acc[2], ga[k].z, da[k]); pkfma(acc[3], ga[k].w, da[k]);
        }
#pragma unroll
        for (int k = 0; k < 4; ++k) {
            int ro = __builtin_amdgcn_ds_bpermute(bidx + ((8 + k) << 2), off);
            float f = __int_as_float(__builtin_amdgcn_ds_bpermute(bidx + ((8 + k) << 2), dni));
            da[k].x = f; da[k].y = f;
            ga[k] = *(const uint4*)(hb + (unsigned)(ro + lane_byte));
        }
#pragma unroll
        for (int k = 0; k < 4; ++k) {
            pkfma(acc[0], gb[k].x, db[k]); pkfma(acc[1], gb[k].y, db[k]);
            pkfma(acc[2], gb[k].z, db[k]); pkfma(acc[3], gb[k].w, db[k]);
        }
#pragma unroll
        for (int k = 0; k < 4; ++k) {
            int ro = __builtin_amdgcn_ds_bpermute(bidx + ((12 + k) << 2), off);
            float f = __int_as_float(__builtin_amdgcn_ds_bpermute(bidx + ((12 + k) << 2), dni));
            db[k].x = f; db[k].y = f;
            gb[k] = *(const uint4*)(hb + (unsigned)(ro + lane_byte));
        }
#pragma unroll
        for (int k = 0; k < 4; ++k) {
            pkfma(acc[0], ga[k].x, da[k]); pkfma(acc[1], ga[k].y, da[k]);
            pkfma(acc[2], ga[k].z, da[k]); pkfma(acc[3], ga[k].w, da[k]);
        }
#pragma unroll
        for (int k = 0; k < 4; ++k) {
            pkfma(acc[0], gb[k].x, db[k]); pkfma(acc[1], gb[k].y, db[k]);
            pkfma(acc[2], gb[k].z, db[k]); pkfma(acc[3], gb[k].w, db[k]);
        }

        off = offn; dnv = dnn;
    }

    float v[8];
    v[0] = dn * acc[0].x + bv0.x;  v[1] = dn * acc[0].y + bv0.y;
    v[2] = dn * acc[1].x + bv0.z;  v[3] = dn * acc[1].y + bv0.w;
    v[4] = dn * acc[2].x + bv1.x;  v[5] = dn * acc[2].y + bv1.y;
    v[6] = dn * acc[3].x + bv1.z;  v[7] = dn * acc[3].y + bv1.w;

    float lmin = v[0], lmax = v[0];
#pragma unroll
    for (int i = 1; i < 8; ++i) { lmin = fminf(lmin, v[i]); lmax = fmaxf(lmax, v[i]); }
#pragma unroll
    for (int m = 8; m; m >>= 1) {
        lmin = fminf(lmin, __shfl_xor(lmin, m, 64));
        lmax = fmaxf(lmax, __shfl_xor(lmax, m, 64));
    }
    float scale = 1.0f / (lmax - lmin);
    float z[8];
    float ss = 0.f;
#pragma unroll
    for (int i = 0; i < 8; ++i) { z[i] = (v[i] - lmin) * scale; ss += z[i] * z[i]; }
#pragma unroll
    for (int m = 8; m; m >>= 1) ss += __shfl_xor(ss, m, 64);
    float inv = 1.0f / fmaxf(sqrtf(ss), 1e-12f);

    float4 o0 = {z[0] * inv, z[1] * inv, z[2] * inv, z[3] * inv};
    float4 o1 = {z[4] * inv, z[5] * inv, z[6] * inv, z[7] * inv};
    float4* op = (float4*)(out + (size_t)node * OUT_CH);
    op[ll * 2] = o0;
    op[ll * 2 + 1] = o1;
}

extern "C" void kernel_launch(void* const* d_in, const int* in_sizes, int n_in,
                              void* d_out, int out_size, void* d_ws, size_t ws_size,
                              hipStream_t stream) {
    const float* x = (const float*)d_in[0];        // fp32 [N, 256]
    const int* ei = (const int*)d_in[1];           // int32 [2, E]
    const float* W = (const float*)d_in[2];        // fp32 [256, 128]
    const float* b = (const float*)d_in[3];        // fp32 [128]
    float* out = (float*)d_out;                    // fp32 [N, 128]

    char* ws = (char*)d_ws;
    size_t o = 0;
    auto alloc = [&](size_t bytes) { void* p = ws + o; o = (o + bytes + 255) & ~(size_t)255; return p; };
    float* dinv    = (float*)alloc((size_t)N_NODES * 4);
    int*   cnt     = (int*)  alloc((size_t)N_NODES * 4);
    int*   base    = (int*)  alloc((size_t)N_NODES * 4);
    int*   bcursor = (int*)  alloc((size_t)NBUCK * 4);
    unsigned short* wb_hi = (unsigned short*)alloc((size_t)IN_CH * OUT_CH * 2);
    unsigned short* wb_lo = (unsigned short*)alloc((size_t)IN_CH * OUT_CH * 2);
    unsigned short* hbs = (unsigned short*)alloc((size_t)(N_NODES + 1) * OUT_CH * 2);  // +1 zero row
    unsigned* ebuf = (unsigned*)alloc((size_t)NBUCK * BCAP * 4);
    int*   es      = (int*)  alloc((size_t)NBUCK * BCAP * 4);

    const int* rows = ei;
    const int* cols = ei + N_EDGES;

    // init: W prep + zero bcursor + zero row
    k_init<<<PREPB, 512, 0, stream>>>(W, wb_hi, wb_lo, bcursor,
                                      (unsigned*)(hbs + (size_t)N_NODES * OUT_CH));

    // launch A: coarse edge scatter || gemm rows 0..32767
    k_mainA<<<SCB + GEMMA, 512, 0, stream>>>(rows, cols, bcursor, ebuf,
                                             x, wb_hi, wb_lo, hbs);

    // launch B: per-bucket sort (cnt/base/dinv/es) || gemm rows 32768..99999
    k_mainB<<<NBUCK + GEMMB, 512, 0, stream>>>(ebuf, bcursor, cnt, base, dinv, es,
                                               x, wb_hi, wb_lo, hbs);

    // fused aggregate + scale + normalize
    k_agg_fin<<<N_NODES / 16, 256, 0, stream>>>(hbs, dinv, es, base, cnt, b, out);
}